// Round 10
// baseline (113.360 us; speedup 1.0000x reference)
//
#include <hip/hip_runtime.h>

// ante[e, i*3+j] = exp(-2*(x1 - c_i)^2) * exp(-2*(x2 - c_j)^2)
// x1 = feat[dst][0] - feat[src][0], x2 = feat[dst][1] - feat[src][1]
//
// R10: single-wave blocks (TPB=64). Converged model: the op is bound by L2
// line-request throughput (~17.2M requests: 12.8M random gathers + 3.6M
// store lines + 0.8M edge reads; rate ~184K req/us calibrated on R6-K1
// => ~93.5us; R4 measured 97.3). This round removes the last untested
// structural suspect -- block-wide barrier convoying -- WITHOUT R9's
// scheduler pinning: a 1-wave block's s_barrier retires immediately, so
// every wave free-runs with full compiler scheduling freedom.
// 32 blocks/CU (4.6KB LDS each), structure otherwise = R4 best (97.3us):
// 2 edges/thread, bank-floor ds_write_b64, contiguous 1KB/instr f4 stores.
// Pre-commit: 93-97us => roofline (L2 request rate); 80-88 => convoy real.

#define TPB 64

typedef float  f2 __attribute__((ext_vector_type(2)));
typedef float  f4 __attribute__((ext_vector_type(4)));
typedef int    i2 __attribute__((ext_vector_type(2)));

__global__ __launch_bounds__(TPB, 8) void ante_kernel(
    const float* __restrict__ feat,
    const int*   __restrict__ esrc,
    const int*   __restrict__ edst,
    float*       __restrict__ out)
{
    __shared__ float lds[18 * TPB];   // 4.6 KB -> 32 blocks/CU
    const int tid = threadIdx.x;
    const size_t t = (size_t)blockIdx.x * TPB + tid;   // 2-edge group id

    // coalesced edge-index loads (8B/lane, 512B/instr)
    const i2 s2 = __builtin_nontemporal_load(reinterpret_cast<const i2*>(esrc) + t);
    const i2 d2 = __builtin_nontemporal_load(reinterpret_cast<const i2*>(edst) + t);

    // 4 scattered gathers, issued back-to-back (want L2 hits -> cached)
    const f2 fs0 = *reinterpret_cast<const f2*>(feat + (size_t)s2.x * 8);
    const f2 fd0 = *reinterpret_cast<const f2*>(feat + (size_t)d2.x * 8);
    const f2 fs1 = *reinterpret_cast<const f2*>(feat + (size_t)s2.y * 8);
    const f2 fd1 = *reinterpret_cast<const f2*>(feat + (size_t)d2.y * 8);

    float m1a[3], m2a[3], m1b[3], m2b[3];
    {
        const float x = fd0.x - fs0.x, a = x + 1.0f, c = x - 1.0f;
        m1a[0] = __expf(-2.0f * a * a); m1a[1] = __expf(-2.0f * x * x); m1a[2] = __expf(-2.0f * c * c);
    }
    {
        const float x = fd0.y - fs0.y, a = x + 1.0f, c = x - 1.0f;
        m2a[0] = __expf(-2.0f * a * a); m2a[1] = __expf(-2.0f * x * x); m2a[2] = __expf(-2.0f * c * c);
    }
    {
        const float x = fd1.x - fs1.x, a = x + 1.0f, c = x - 1.0f;
        m1b[0] = __expf(-2.0f * a * a); m1b[1] = __expf(-2.0f * x * x); m1b[2] = __expf(-2.0f * c * c);
    }
    {
        const float x = fd1.y - fs1.y, a = x + 1.0f, c = x - 1.0f;
        m2b[0] = __expf(-2.0f * a * a); m2b[1] = __expf(-2.0f * x * x); m2b[2] = __expf(-2.0f * c * c);
    }

    // 9 x ds_write_b64 at f2 slot lane*9 (bank-floor pattern, 8B aligned)
    f2* my2 = reinterpret_cast<f2*>(lds) + tid * 9;
    f2 v;
    v.x = m1a[0] * m2a[0]; v.y = m1a[0] * m2a[1]; my2[0] = v;
    v.x = m1a[0] * m2a[2]; v.y = m1a[1] * m2a[0]; my2[1] = v;
    v.x = m1a[1] * m2a[1]; v.y = m1a[1] * m2a[2]; my2[2] = v;
    v.x = m1a[2] * m2a[0]; v.y = m1a[2] * m2a[1]; my2[3] = v;
    v.x = m1a[2] * m2a[2]; v.y = m1b[0] * m2b[0]; my2[4] = v;
    v.x = m1b[0] * m2b[1]; v.y = m1b[0] * m2b[2]; my2[5] = v;
    v.x = m1b[1] * m2b[0]; v.y = m1b[1] * m2b[1]; my2[6] = v;
    v.x = m1b[1] * m2b[2]; v.y = m1b[2] * m2b[0]; my2[7] = v;
    v.x = m1b[2] * m2b[1]; v.y = m1b[2] * m2b[2]; my2[8] = v;

    // single-wave block: s_barrier is trivial, just orders LDS (lgkmcnt)
    __syncthreads();

    // Store phase: block covers 128 edges -> 288 contiguous f4 (4.6KB).
    // f4 slot f = k*64+tid is both the LDS index and the output offset.
    const f4* lds4 = reinterpret_cast<const f4*>(lds);
    f4* out4 = reinterpret_cast<f4*>(out);
    const size_t ob = (size_t)blockIdx.x * (TPB * 9 / 2);   // 288 f4/block
#pragma unroll
    for (int k = 0; k < 5; ++k) {
        const int f = k * TPB + tid;
        if (f < TPB * 9 / 2)
            __builtin_nontemporal_store(lds4[f], out4 + ob + f);
    }
}

extern "C" void kernel_launch(void* const* d_in, const int* in_sizes, int n_in,
                              void* d_out, int out_size, void* d_ws, size_t ws_size,
                              hipStream_t stream) {
    const float* feat = (const float*)d_in[0];
    const int*   esrc = (const int*)d_in[1];
    const int*   edst = (const int*)d_in[2];
    float* out = (float*)d_out;

    const int E  = in_sizes[1];          // 6,400,000
    const int e2 = E / 2;                // 3,200,000 2-edge groups
    const int grid = e2 / TPB;           // 50,000 exact
    ante_kernel<<<grid, TPB, 0, stream>>>(feat, esrc, edst, out);
}

// Round 11
// 97.243 us; speedup vs baseline: 1.1657x; 1.1657x over previous
//
#include <hip/hip_runtime.h>

// ante[e, i*3+j] = exp(-2*(x1 - c_i)^2) * exp(-2*(x2 - c_j)^2)
// x1 = feat[dst][0] - feat[src][0], x2 = feat[dst][1] - feat[src][1]
// c = {-1, 0, +1}, 1/(2*sigma^2) = 2.0
//
// FINAL (= R4, best of 10 structural experiments at 97.3us).
// Structure: 2 edges/thread; coalesced i2 edge-index loads; 4 scattered f2
// gathers (L2-resident feat); 9 x ds_write_b64 LDS transpose (bank-floor);
// ds_read_b128 + contiguous 1KB-per-instruction f4 global stores.
// Why this is the floor: the op issues ~17.2M L2 line-requests (12.8M
// irreducible random gathers + 3.6M store lines + 0.8M edge reads) at the
// measured ~184K req/us TA/L2 request rate (calibrated on a pure-gather
// kernel: 13.6M req / 74us) => ~93.5us model floor; this kernel = 97.3us.
// Occupancy x2, footprint /4, MLP x4, phase-split, persistent pipeline,
// barrier-free, and 1-wave-block variants all measured nil or negative --
// consistent with the request-rate model (none reduce request count).

#define TPB 256

typedef float  f2 __attribute__((ext_vector_type(2)));
typedef float  f4 __attribute__((ext_vector_type(4)));
typedef int    i2 __attribute__((ext_vector_type(2)));

__global__ __launch_bounds__(TPB, 8) void ante_kernel(
    const float* __restrict__ feat,
    const int*   __restrict__ esrc,
    const int*   __restrict__ edst,
    float*       __restrict__ out,
    int e2,      // number of 2-edge groups
    int nf4)     // total output float4 count
{
    __shared__ float lds[TPB * 18];   // 18 KB/block -> 8 blocks/CU
    const int tid = threadIdx.x;
    const int t   = blockIdx.x * TPB + tid;

    if (t < e2) {
        const i2 s2 = __builtin_nontemporal_load(reinterpret_cast<const i2*>(esrc) + t);
        const i2 d2 = __builtin_nontemporal_load(reinterpret_cast<const i2*>(edst) + t);

        // Issue all 4 gathers before any arithmetic (maximize MLP).
        const f2 fs0 = *reinterpret_cast<const f2*>(feat + (size_t)s2.x * 8);
        const f2 fd0 = *reinterpret_cast<const f2*>(feat + (size_t)d2.x * 8);
        const f2 fs1 = *reinterpret_cast<const f2*>(feat + (size_t)s2.y * 8);
        const f2 fd1 = *reinterpret_cast<const f2*>(feat + (size_t)d2.y * 8);

        float res[18];
#pragma unroll
        for (int q = 0; q < 2; ++q) {
            const float x1 = (q == 0) ? (fd0.x - fs0.x) : (fd1.x - fs1.x);
            const float x2 = (q == 0) ? (fd0.y - fs0.y) : (fd1.y - fs1.y);

            float m1[3], m2[3];
            {
                const float a = x1 + 1.0f, c = x1 - 1.0f;
                m1[0] = __expf(-2.0f * a * a);
                m1[1] = __expf(-2.0f * x1 * x1);
                m1[2] = __expf(-2.0f * c * c);
            }
            {
                const float a = x2 + 1.0f, c = x2 - 1.0f;
                m2[0] = __expf(-2.0f * a * a);
                m2[1] = __expf(-2.0f * x2 * x2);
                m2[2] = __expf(-2.0f * c * c);
            }
#pragma unroll
            for (int i = 0; i < 3; ++i)
#pragma unroll
                for (int j = 0; j < 3; ++j)
                    res[q * 9 + i * 3 + j] = m1[i] * m2[j];
        }

        // 9 x ds_write_b64, dword base 18*tid (8B aligned), bank-floor pattern.
        f2* my2 = reinterpret_cast<f2*>(lds) + tid * 9;
#pragma unroll
        for (int k = 0; k < 9; ++k) {
            f2 v; v.x = res[2 * k]; v.y = res[2 * k + 1];
            my2[k] = v;
        }
    }
    __syncthreads();

    // Store phase: float4 slot f = k*TPB+tid is both LDS f4 index and the
    // output f4 index within the block's span (1152 f4 per block).
    const size_t blk_f4 = (size_t)blockIdx.x * (TPB * 9 / 2);
    f4* out4 = reinterpret_cast<f4*>(out);
    const f4* lds4 = reinterpret_cast<const f4*>(lds);

#pragma unroll
    for (int k = 0; k < 5; ++k) {
        const int f = k * TPB + tid;
        if (f < TPB * 9 / 2) {
            const size_t g = blk_f4 + (size_t)f;
            if (g < (size_t)nf4)
                __builtin_nontemporal_store(lds4[f], out4 + g);
        }
    }
}

extern "C" void kernel_launch(void* const* d_in, const int* in_sizes, int n_in,
                              void* d_out, int out_size, void* d_ws, size_t ws_size,
                              hipStream_t stream) {
    const float* feat = (const float*)d_in[0];
    const int*   esrc = (const int*)d_in[1];
    const int*   edst = (const int*)d_in[2];
    // d_in[3] = etypes, unused by the reference output
    float* out = (float*)d_out;

    const int E   = in_sizes[1];         // 6,400,000
    const int e2  = E / 2;               // 2-edge groups (E divisible by 2)
    const int nf4 = out_size / 4;        // output float4 count
    const int grid = (e2 + TPB - 1) / TPB;
    ante_kernel<<<grid, TPB, 0, stream>>>(feat, esrc, edst, out, e2, nf4);
}